// Round 2
// baseline (9377.232 us; speedup 1.0000x reference)
//
#include <hip/hip_runtime.h>
#include <hip/hip_bf16.h>

// ---------------------------------------------------------------------------
// LSTM_66675072303478: 2-layer LSTM (B=512,S=128,E=7,H=1024) + FC(1024->672)
//
// v2 changes vs v1:
//  - h stored in MFMA-A-fragment-swizzled layout -> A loaded direct from L2,
//    no LDS staging for A (removes 1/3 of LDS traffic).
//  - 512 threads/block (8 waves, 2 waves/SIMD) via in-block split-K: wave
//    group 0 does even 32-k chunks, group 1 odd; fp32 partial merge via LDS.
//  - BK=64 super-iters halve barrier count.
// Weights remain gate-interleaved bf16 so the LSTM cell update fuses into the
// GEMM epilogue (i,f,g,o for one hidden column land in one lane's 4 frags).
// ---------------------------------------------------------------------------

typedef __bf16 bf16x8 __attribute__((ext_vector_type(8)));
typedef float  f32x4  __attribute__((ext_vector_type(4)));

#define BLSTR 36   // Blds row stride in bf16 elems (32 data + 4 pad -> <=2-way)

__device__ __forceinline__ float sigm_f(float x) {
    x = fminf(30.f, fmaxf(-30.f, x));
    return 1.0f / (1.0f + __expf(-x));
}
__device__ __forceinline__ float tanh_f(float x) {
    x = fminf(30.f, fmaxf(-30.f, x));
    float e = __expf(-2.0f * x);
    return (1.0f - e) / (1.0f + e);
}

// n' = (j/16)*64 + g*16 + (j%16)  ->  original gate-major row g*1024 + j
__device__ __forceinline__ int perm_row(int np) {
    int g = (np >> 4) & 3;
    int j = ((np >> 6) << 4) | (np & 15);
    return g * 1024 + j;
}

// ---------------- weight prep kernels (run every call; ws is re-poisoned) ---

__global__ void prep_w0(const float* __restrict__ Wh0, __bf16* __restrict__ W0p) {
    int idx = blockIdx.x * 256 + threadIdx.x;      // 4096 rows x 256 thr (x4 elems)
    int np = idx >> 8, k4 = (idx & 255) << 2;
    int r = perm_row(np);
    float4 v = *(const float4*)(Wh0 + r * 1024 + k4);
    __bf16* o = W0p + np * 1024 + k4;
    o[0] = (__bf16)v.x; o[1] = (__bf16)v.y; o[2] = (__bf16)v.z; o[3] = (__bf16)v.w;
}

__global__ void prep_w1(const float* __restrict__ Wi1, const float* __restrict__ Wh1,
                        __bf16* __restrict__ W1p) {
    int idx = blockIdx.x * 256 + threadIdx.x;      // 4096 rows x 512 thr (x4 elems)
    int np = idx >> 9, k4 = (idx & 511) << 2;
    int r = perm_row(np);
    const float* s = (k4 < 1024) ? (Wi1 + r * 1024 + k4) : (Wh1 + r * 1024 + (k4 - 1024));
    float4 v = *(const float4*)s;
    __bf16* o = W1p + np * 2048 + k4;
    o[0] = (__bf16)v.x; o[1] = (__bf16)v.y; o[2] = (__bf16)v.z; o[3] = (__bf16)v.w;
}

__global__ void prep_wfc(const float* __restrict__ Wfc, __bf16* __restrict__ Wfcp) {
    int idx = blockIdx.x * 256 + threadIdx.x;      // 768 rows x 256 thr (x4 elems)
    int n = idx >> 8, k4 = (idx & 255) << 2;
    __bf16* o = Wfcp + n * 1024 + k4;
    if (n < 672) {
        float4 v = *(const float4*)(Wfc + n * 1024 + k4);
        o[0] = (__bf16)v.x; o[1] = (__bf16)v.y; o[2] = (__bf16)v.z; o[3] = (__bf16)v.w;
    } else {
        o[0] = (__bf16)0.f; o[1] = (__bf16)0.f; o[2] = (__bf16)0.f; o[3] = (__bf16)0.f;
    }
}

__global__ void prep_small(const float* __restrict__ Wi0, const float* __restrict__ b0,
                           const float* __restrict__ b1,
                           float* __restrict__ Wi0p, float* __restrict__ b1p) {
    int np = blockIdx.x * 256 + threadIdx.x;       // 4096 threads
    int r = perm_row(np);
    float* o = Wi0p + np * 8;
    #pragma unroll
    for (int q = 0; q < 7; ++q) o[q] = Wi0[r * 7 + q];
    o[7] = b0[r];
    b1p[np] = b1[r];
}

// ---------------- fused GEMM + LSTM-cell / FC kernel ------------------------
// Tile: BM=64 x BN=128, 512 threads = 8 waves: group g=w>>2 splits K (even/odd
// 32-chunks of a BK=64 super-iter), within group 2x2 waves of 32x64.
// A (activations) loaded direct from global in swizzled fragment layout:
//   elem(m,k) = (((m>>4)*64 + (k>>5))*64 + ((m&15)|(((k>>3)&3)<<4)))*8 + (k&7)
// EPI: 0 = LSTM layer0 (x-dot + b0 in epilogue), 1 = LSTM layer1 (+b1),
//      2 = FC (write fp32 out + bfc, guard n<672).

__device__ __forceinline__ uint4 ldA(const __bf16* __restrict__ A0,
                                     const __bf16* __restrict__ A1,
                                     int mt, int kblk, int l) {
    const __bf16* base = (kblk < 32) ? A0 : A1;
    return ((const uint4*)base)[(mt * 64 + kblk) * 64 + l];
}

template <int KTOT, int EPI>
__global__ __launch_bounds__(512)
void gemm2(const __bf16* __restrict__ A0,   // A base for kblk in [0,32)
           const __bf16* __restrict__ A1,   // A base for kblk in [32,64)
           const __bf16* __restrict__ W,    // (N x KTOT) bf16, row-major
           const float* __restrict__ aux,   // EPI0: Wi0p(4096x8); EPI1: b1p; EPI2: bfc
           const float* __restrict__ xt,    // EPI0: x + t*7 (row stride 896)
           float* __restrict__ Cst,         // EPI0/1: c-state (512x1024); EPI2: out
           __bf16* __restrict__ Hsw,        // EPI0/1: swizzled h dest buffer
           int joff,                        // 0 (h_a) or 1024 (h_b)
           int kblk_off)                    // 0, or 32 for FC (h_b half)
{
    constexpr int NIT = KTOT / 64;
    __shared__ __attribute__((aligned(16))) __bf16 Blds[2][128 * BLSTR];
    __shared__ __attribute__((aligned(16))) float  Rbuf[8 * 256 * 4];   // 32 KB
    __shared__ float Aux1[128];
    __shared__ float Xlds[64 * 9];
    __shared__ float Wxlds[128 * 9];

    const int tid = threadIdx.x;
    const int n0 = blockIdx.x * 128;
    const int m0 = blockIdx.y * 64;

    // stage epilogue inputs
    if (EPI == 0) {
        if (tid < 64) {
            const float* xr = xt + (m0 + tid) * 896;
            float* d = Xlds + tid * 9;
            #pragma unroll
            for (int q = 0; q < 7; ++q) d[q] = xr[q];
            d[7] = 1.0f;
        } else if (tid < 192) {
            int nl = tid - 64;
            const float* s = aux + (n0 + nl) * 8;
            float* d = Wxlds + nl * 9;
            #pragma unroll
            for (int q = 0; q < 8; ++q) d[q] = s[q];
        }
    } else {
        if (tid < 128) {
            int n = n0 + tid;
            Aux1[tid] = (EPI == 1) ? aux[n] : ((n < 672) ? aux[n] : 0.0f);
        }
    }

    // B staging map: thread -> row tid/4 (0..127), 8-elem col chunk (tid%4)*8
    const int srow = tid >> 2;
    const int scol = (tid & 3) << 3;
    const __bf16* wrow = W + (size_t)(n0 + srow) * KTOT + scol;

    const int l  = tid & 63, w = tid >> 6;
    const int g  = w >> 2,  wq = w & 3;
    const int wm = wq & 1,  wn = wq >> 1;
    const int lj = l & 15,  lq = l >> 4;
    const int mt0 = (m0 >> 4) + wm * 2;

    // prefetch super-iter 0
    uint4 br0 = *(const uint4*)(wrow);          // chunk 0 (k0..k0+31)
    uint4 br1 = *(const uint4*)(wrow + 32);     // chunk 1 (k0+32..k0+63)
    uint4 an0, an1;
    {
        int kb = g + kblk_off;
        an0 = ldA(A0, A1, mt0,     kb, l);
        an1 = ldA(A0, A1, mt0 + 1, kb, l);
    }

    f32x4 acc[2][4];
    #pragma unroll
    for (int i = 0; i < 2; ++i)
        #pragma unroll
        for (int j = 0; j < 4; ++j)
            acc[i][j] = (f32x4){0.f, 0.f, 0.f, 0.f};

    const __bf16* brd = Blds[g] + (wn * 64 + lj) * BLSTR + lq * 8;

    for (int it = 0; it < NIT; ++it) {
        __syncthreads();
        *(uint4*)(Blds[0] + srow * BLSTR + scol) = br0;
        *(uint4*)(Blds[1] + srow * BLSTR + scol) = br1;
        __syncthreads();
        uint4 ac0 = an0, ac1 = an1;
        if (it + 1 < NIT) {
            const __bf16* wr = wrow + (it + 1) * 64;
            br0 = *(const uint4*)(wr);
            br1 = *(const uint4*)(wr + 32);
            int kb = (it + 1) * 2 + g + kblk_off;
            an0 = ldA(A0, A1, mt0,     kb, l);
            an1 = ldA(A0, A1, mt0 + 1, kb, l);
        }
        bf16x8 af0 = *(bf16x8*)&ac0;
        bf16x8 af1 = *(bf16x8*)&ac1;
        #pragma unroll
        for (int ni = 0; ni < 4; ++ni) {
            bf16x8 bfr = *(const bf16x8*)(brd + ni * 16 * BLSTR);
            acc[0][ni] = __builtin_amdgcn_mfma_f32_16x16x32_bf16(af0, bfr, acc[0][ni], 0, 0, 0);
            acc[1][ni] = __builtin_amdgcn_mfma_f32_16x16x32_bf16(af1, bfr, acc[1][ni], 0, 0, 0);
        }
    }

    // ---- split-K merge: group 1 -> LDS -> group 0 adds ----
    if (g == 1) {
        #pragma unroll
        for (int mi = 0; mi < 2; ++mi)
            #pragma unroll
            for (int ni = 0; ni < 4; ++ni)
                *(f32x4*)(Rbuf + (((mi * 4 + ni) * 256) + wq * 64 + l) * 4) = acc[mi][ni];
    }
    __syncthreads();
    if (g == 0) {
        #pragma unroll
        for (int mi = 0; mi < 2; ++mi)
            #pragma unroll
            for (int ni = 0; ni < 4; ++ni)
                acc[mi][ni] += *(const f32x4*)(Rbuf + (((mi * 4 + ni) * 256) + wq * 64 + l) * 4);

        // ---- epilogue (group 0 only: 256 threads cover the 64x128 tile) ----
        if (EPI == 2) {
            #pragma unroll
            for (int mi = 0; mi < 2; ++mi) {
                #pragma unroll
                for (int r = 0; r < 4; ++r) {
                    int m = m0 + wm * 32 + mi * 16 + lq * 4 + r;
                    #pragma unroll
                    for (int ni = 0; ni < 4; ++ni) {
                        int n = n0 + wn * 64 + ni * 16 + lj;
                        if (n < 672)
                            Cst[m * 672 + n] = acc[mi][ni][r] + Aux1[wn * 64 + ni * 16 + lj];
                    }
                }
            }
        } else {
            #pragma unroll
            for (int mi = 0; mi < 2; ++mi) {
                #pragma unroll
                for (int r = 0; r < 4; ++r) {
                    int ml = wm * 32 + mi * 16 + lq * 4 + r;
                    int m  = m0 + ml;
                    float pre[4];
                    #pragma unroll
                    for (int gg = 0; gg < 4; ++gg) pre[gg] = acc[mi][gg][r];
                    if (EPI == 0) {
                        const float* xr = Xlds + ml * 9;
                        #pragma unroll
                        for (int gg = 0; gg < 4; ++gg) {
                            const float* wx = Wxlds + (wn * 64 + gg * 16 + lj) * 9;
                            float s = 0.f;
                            #pragma unroll
                            for (int q = 0; q < 8; ++q) s += xr[q] * wx[q];
                            pre[gg] += s;
                        }
                    } else {
                        #pragma unroll
                        for (int gg = 0; gg < 4; ++gg) pre[gg] += Aux1[wn * 64 + gg * 16 + lj];
                    }
                    int jc = (n0 >> 2) + wn * 16 + lj;     // hidden column (layer-local)
                    float* cp = Cst + m * 1024 + jc;
                    float cold = *cp;
                    float ig = sigm_f(pre[0]);
                    float fg = sigm_f(pre[1]);
                    float gv = tanh_f(pre[2]);
                    float og = sigm_f(pre[3]);
                    float cn = fg * cold + ig * gv;
                    *cp = cn;
                    float hv = og * tanh_f(cn);
                    // swizzled store into A-fragment layout
                    int j = joff + jc;
                    int mtile = mt0 + mi;                  // m>>4
                    int lane_s = (lq * 4 + r) | (((j >> 3) & 3) << 4);
                    Hsw[((mtile * 64 + (j >> 5)) * 64 + lane_s) * 8 + (j & 7)] = (__bf16)hv;
                }
            }
        }
    }
}

// ---------------- workspace layout (bytes) ----------------------------------
#define O_W0P   0u            // 4096*1024*2  = 8388608
#define O_W1P   8388608u      // 4096*2048*2  = 16777216
#define O_WFCP  25165824u     // 768*1024*2   = 1572864
#define O_WI0P  26738688u     // 4096*8*4     = 131072
#define O_B1P   26869760u     // 4096*4       = 16384
#define O_AB0   26886144u     // 512*2048*2   = 2097152 (swizzled)
#define O_CA    28983296u     // 512*1024*4   = 2097152
#define O_CB    31080448u     // 512*1024*4   = 2097152
#define O_AB1   33177600u     // 512*2048*2   = 2097152 (swizzled)
#define WS_NEED 35274752u

extern "C" void kernel_launch(void* const* d_in, const int* in_sizes, int n_in,
                              void* d_out, int out_size, void* d_ws, size_t ws_size,
                              hipStream_t stream) {
    const float* x   = (const float*)d_in[0];
    const float* Wi0 = (const float*)d_in[1];
    const float* Wh0 = (const float*)d_in[2];
    const float* b0  = (const float*)d_in[3];
    const float* Wi1 = (const float*)d_in[4];
    const float* Wh1 = (const float*)d_in[5];
    const float* b1  = (const float*)d_in[6];
    const float* Wfc = (const float*)d_in[7];
    const float* bfc = (const float*)d_in[8];
    float* out = (float*)d_out;
    char*  ws  = (char*)d_ws;
    if (ws_size < WS_NEED) return;

    __bf16* W0p  = (__bf16*)(ws + O_W0P);
    __bf16* W1p  = (__bf16*)(ws + O_W1P);
    __bf16* Wfcp = (__bf16*)(ws + O_WFCP);
    float*  Wi0p = (float*)(ws + O_WI0P);
    float*  b1p  = (float*)(ws + O_B1P);
    __bf16* Ab0  = (__bf16*)(ws + O_AB0);
    float*  ca   = (float*)(ws + O_CA);
    float*  cb   = (float*)(ws + O_CB);
    __bf16* Ab1  = (__bf16*)(ws + O_AB1);

    // zero h ping buffer 0 + both c states (contiguous 6 MB region)
    hipMemsetAsync(ws + O_AB0, 0, 3u * 2097152u, stream);

    prep_w0   <<<4096, 256, 0, stream>>>(Wh0, W0p);
    prep_w1   <<<8192, 256, 0, stream>>>(Wi1, Wh1, W1p);
    prep_wfc  <<<768,  256, 0, stream>>>(Wfc, Wfcp);
    prep_small<<<16,   256, 0, stream>>>(Wi0, b0, b1, Wi0p, b1p);

    dim3 blk(512), gl(32, 8);
    for (int t = 0; t < 128; ++t) {
        __bf16* Acur = (t & 1) ? Ab1 : Ab0;
        __bf16* Anxt = (t & 1) ? Ab0 : Ab1;
        // layer 0: gates = h_a(t-1) @ Wh0p^T (+ x_t@Wi0^T + b0 in epilogue)
        gemm2<1024, 0><<<gl, blk, 0, stream>>>(Acur, Acur, W0p, Wi0p,
                                               x + t * 7, ca, Anxt, 0, 0);
        // layer 1: gates = [h_a(t) | h_b(t-1)] @ [Wi1|Wh1]p^T + b1
        //   kblk<32 -> h_a(t) in Anxt; kblk>=32 -> h_b(t-1) in Acur
        gemm2<2048, 1><<<gl, blk, 0, stream>>>(Anxt, Acur, W1p, b1p,
                                               nullptr, cb, Anxt, 1024, 0);
    }
    // final h_b lives in Ab0 kblk 32..63 (t=127 wrote buffer 0)
    dim3 gf(6, 8);
    gemm2<1024, 2><<<gf, blk, 0, stream>>>(Ab0, Ab0, Wfcp, bfc,
                                           nullptr, out, nullptr, 0, 32);
}

// Round 3
// 8907.291 us; speedup vs baseline: 1.0528x; 1.0528x over previous
//
#include <hip/hip_runtime.h>
#include <hip/hip_bf16.h>

// ---------------------------------------------------------------------------
// LSTM_66675072303478: 2-layer LSTM (B=512,S=128,E=7,H=1024) + FC(1024->672)
//
// v3: single persistent kernel, 256 blocks (1/CU), 128-step loop inside.
//  - Cross-block sync via per-m-group epoch counters (release atomicAdd /
//    acquire spin), replacing 257 kernel launches.
//  - v1's proven K-loop (LDS-staged A+B, BK=32, reg prefetch) kept verbatim.
//  - c-state lives in 16 registers/thread (block owns fixed (m,j) slice).
//  - Gate-interleaved bf16 weights; LSTM cell fused into GEMM epilogue.
// ---------------------------------------------------------------------------

typedef __bf16 bf16x8 __attribute__((ext_vector_type(8)));
typedef float  f32x4  __attribute__((ext_vector_type(4)));

#define LDST 40   // LDS row stride in bf16 elems (32 data + 8 pad)

__device__ __forceinline__ float sigm_f(float x) {
    x = fminf(30.f, fmaxf(-30.f, x));
    return 1.0f / (1.0f + __expf(-x));
}
__device__ __forceinline__ float tanh_f(float x) {
    x = fminf(30.f, fmaxf(-30.f, x));
    float e = __expf(-2.0f * x);
    return (1.0f - e) / (1.0f + e);
}

// n' = (j/16)*64 + g*16 + (j%16)  ->  original gate-major row g*1024 + j
__device__ __forceinline__ int perm_row(int np) {
    int g = (np >> 4) & 3;
    int j = ((np >> 6) << 4) | (np & 15);
    return g * 1024 + j;
}

// ---- flag sync helpers (agent scope: cross-XCD L2 maintenance included) ----
__device__ __forceinline__ void spin_ge(const int* p, int target) {
    while (__hip_atomic_load(p, __ATOMIC_RELAXED, __HIP_MEMORY_SCOPE_AGENT) < target)
        __builtin_amdgcn_s_sleep(2);
    (void)__hip_atomic_load(p, __ATOMIC_ACQUIRE, __HIP_MEMORY_SCOPE_AGENT);
}
__device__ __forceinline__ void signal_inc(int* p) {
    __hip_atomic_fetch_add(p, 1, __ATOMIC_RELEASE, __HIP_MEMORY_SCOPE_AGENT);
}

// ---------------- weight prep kernels (run every call) ----------------------

__global__ void prep_w0(const float* __restrict__ Wh0, __bf16* __restrict__ W0p) {
    int idx = blockIdx.x * 256 + threadIdx.x;
    int np = idx >> 8, k4 = (idx & 255) << 2;
    int r = perm_row(np);
    float4 v = *(const float4*)(Wh0 + r * 1024 + k4);
    __bf16* o = W0p + np * 1024 + k4;
    o[0] = (__bf16)v.x; o[1] = (__bf16)v.y; o[2] = (__bf16)v.z; o[3] = (__bf16)v.w;
}

__global__ void prep_w1(const float* __restrict__ Wi1, const float* __restrict__ Wh1,
                        __bf16* __restrict__ W1p) {
    int idx = blockIdx.x * 256 + threadIdx.x;
    int np = idx >> 9, k4 = (idx & 511) << 2;
    int r = perm_row(np);
    const float* s = (k4 < 1024) ? (Wi1 + r * 1024 + k4) : (Wh1 + r * 1024 + (k4 - 1024));
    float4 v = *(const float4*)s;
    __bf16* o = W1p + np * 2048 + k4;
    o[0] = (__bf16)v.x; o[1] = (__bf16)v.y; o[2] = (__bf16)v.z; o[3] = (__bf16)v.w;
}

__global__ void prep_wfc(const float* __restrict__ Wfc, __bf16* __restrict__ Wfcp) {
    int idx = blockIdx.x * 256 + threadIdx.x;
    int n = idx >> 8, k4 = (idx & 255) << 2;
    __bf16* o = Wfcp + n * 1024 + k4;
    if (n < 672) {
        float4 v = *(const float4*)(Wfc + n * 1024 + k4);
        o[0] = (__bf16)v.x; o[1] = (__bf16)v.y; o[2] = (__bf16)v.z; o[3] = (__bf16)v.w;
    } else {
        o[0] = (__bf16)0.f; o[1] = (__bf16)0.f; o[2] = (__bf16)0.f; o[3] = (__bf16)0.f;
    }
}

__global__ void prep_small(const float* __restrict__ Wi0, const float* __restrict__ b0,
                           const float* __restrict__ b1,
                           float* __restrict__ Wi0p, float* __restrict__ b1p) {
    int np = blockIdx.x * 256 + threadIdx.x;
    int r = perm_row(np);
    float* o = Wi0p + np * 8;
    #pragma unroll
    for (int q = 0; q < 7; ++q) o[q] = Wi0[r * 7 + q];
    o[7] = b0[r];
    b1p[np] = b1[r];
}

// ---------------- shared K-loop (v1's proven structure) ---------------------
// Tile 64x128, 256 thr = 4 waves 2x2, wave tile 32x64, BK=32, reg prefetch.
// A rows stride 2048. DUAL: k<1024 from A0, k>=1024 from A1 (same k offset).

template <int KTOT, bool DUAL>
__device__ __forceinline__ void kloop(const __bf16* __restrict__ A0,
                                      const __bf16* __restrict__ A1,
                                      const __bf16* __restrict__ W,
                                      int n0, int m0, int tid,
                                      __bf16* Alds, __bf16* Blds,
                                      f32x4 (&acc)[2][4]) {
    const int a_r = tid >> 2;
    const int a_c = (tid & 3) << 3;
    const __bf16* wrow = W + (size_t)(n0 + a_r) * KTOT + a_c;

    const int l  = tid & 63, w = tid >> 6;
    const int wm = w & 1,   wn = w >> 1;
    const int lj = l & 15,  lq = l >> 4;

    uint4 ra  = *(const uint4*)(A0 + (m0 + a_r) * 2048 + a_c);
    uint4 rb0 = *(const uint4*)(wrow);
    uint4 rb1 = *(const uint4*)(wrow + (size_t)64 * KTOT);

    #pragma unroll
    for (int i = 0; i < 2; ++i)
        #pragma unroll
        for (int j = 0; j < 4; ++j)
            acc[i][j] = (f32x4){0.f, 0.f, 0.f, 0.f};

    constexpr int NIT = KTOT / 32;
    for (int it = 0; it < NIT; ++it) {
        __syncthreads();
        *(uint4*)(Alds + a_r * LDST + a_c) = ra;
        *(uint4*)(Blds + a_r * LDST + a_c) = rb0;
        *(uint4*)(Blds + (a_r + 64) * LDST + a_c) = rb1;
        __syncthreads();
        if (it + 1 < NIT) {
            int k0 = (it + 1) * 32;
            const __bf16* Ab = (!DUAL || k0 < 1024) ? A0 : A1;
            ra  = *(const uint4*)(Ab + (m0 + a_r) * 2048 + k0 + a_c);
            rb0 = *(const uint4*)(wrow + k0);
            rb1 = *(const uint4*)(wrow + (size_t)64 * KTOT + k0);
        }
        const __bf16* Ap = Alds + (wm * 32 + lj) * LDST + lq * 8;
        bf16x8 af0 = *(const bf16x8*)(Ap);
        bf16x8 af1 = *(const bf16x8*)(Ap + 16 * LDST);
        const __bf16* Bp = Blds + (wn * 64 + lj) * LDST + lq * 8;
        #pragma unroll
        for (int ni = 0; ni < 4; ++ni) {
            bf16x8 bfr = *(const bf16x8*)(Bp + ni * 16 * LDST);
            acc[0][ni] = __builtin_amdgcn_mfma_f32_16x16x32_bf16(af0, bfr, acc[0][ni], 0, 0, 0);
            acc[1][ni] = __builtin_amdgcn_mfma_f32_16x16x32_bf16(af1, bfr, acc[1][ni], 0, 0, 0);
        }
    }
}

// ---------------- persistent LSTM kernel ------------------------------------
// Grid (32,8): nb = gate-column block (128 gates -> 32 h cols), mb = 64 rows.
// cnt[0..7] = cntA (h_a epochs), cnt[8..15] = cntB (h_b epochs).

__global__ __launch_bounds__(256)
void lstm_persist(const float* __restrict__ x,
                  const __bf16* __restrict__ W0p, const __bf16* __restrict__ W1p,
                  const __bf16* __restrict__ Wfcp,
                  const float* __restrict__ Wi0p, const float* __restrict__ b1p,
                  const float* __restrict__ bfc,
                  __bf16* __restrict__ Ab0, __bf16* __restrict__ Ab1,
                  int* __restrict__ cnt, float* __restrict__ out) {
    __shared__ __attribute__((aligned(16))) __bf16 Alds[64 * LDST];
    __shared__ __attribute__((aligned(16))) __bf16 Blds[128 * LDST];
    __shared__ float Aux1[128];
    __shared__ float Xlds[64 * 9];
    __shared__ float Wxlds[128 * 9];

    const int tid = threadIdx.x;
    const int nb = blockIdx.x, mb = blockIdx.y;
    const int n0 = nb * 128, m0 = mb * 64;
    int* cA = cnt + mb;
    int* cB = cnt + 8 + mb;

    // one-time per-block epilogue constants
    if (tid < 128) {
        Aux1[tid] = b1p[n0 + tid];
    } else {
        int nl = tid - 128;
        const float* s = Wi0p + (n0 + nl) * 8;
        float* d = Wxlds + nl * 9;
        #pragma unroll
        for (int q = 0; q < 8; ++q) d[q] = s[q];
    }

    const int l  = tid & 63, w = tid >> 6;
    const int wm = w & 1,   wn = w >> 1;
    const int lj = l & 15,  lq = l >> 4;
    const int jc = (n0 >> 2) + wn * 16 + lj;   // this thread's hidden column

    float c0[2][4], c1[2][4];
    #pragma unroll
    for (int i = 0; i < 2; ++i)
        #pragma unroll
        for (int r = 0; r < 4; ++r) { c0[i][r] = 0.f; c1[i][r] = 0.f; }

    f32x4 acc[2][4];

    for (int t = 0; t < 128; ++t) {
        __bf16* hprev = (t & 1) ? Ab1 : Ab0;   // holds h(t-1); h(-1)=zeros in Ab0
        __bf16* hcur  = (t & 1) ? Ab0 : Ab1;

        // stage x_t (input data: no flag dependency)
        if (tid < 64) {
            const float* xr = x + (m0 + tid) * 896 + t * 7;
            float* d = Xlds + tid * 9;
            #pragma unroll
            for (int q = 0; q < 7; ++q) d[q] = xr[q];
            d[7] = 1.0f;
        }

        // ---- phase 0: gates_a = h_a(t-1) @ Wh0^T (+ x_t dot in epilogue) ----
        if (tid == 0) spin_ge(cA, 32 * t);
        __syncthreads();
        kloop<1024, false>(hprev, nullptr, W0p, n0, m0, tid, Alds, Blds, acc);

        #pragma unroll
        for (int mi = 0; mi < 2; ++mi) {
            #pragma unroll
            for (int r = 0; r < 4; ++r) {
                int ml = wm * 32 + mi * 16 + lq * 4 + r;
                int m  = m0 + ml;
                float pre[4];
                #pragma unroll
                for (int g = 0; g < 4; ++g) pre[g] = acc[mi][g][r];
                const float* xr = Xlds + ml * 9;
                #pragma unroll
                for (int g = 0; g < 4; ++g) {
                    const float* wx = Wxlds + (wn * 64 + g * 16 + lj) * 9;
                    float s = 0.f;
                    #pragma unroll
                    for (int q = 0; q < 8; ++q) s += xr[q] * wx[q];
                    pre[g] += s;
                }
                float ig = sigm_f(pre[0]);
                float fg = sigm_f(pre[1]);
                float gv = tanh_f(pre[2]);
                float og = sigm_f(pre[3]);
                float cn = fg * c0[mi][r] + ig * gv;
                c0[mi][r] = cn;
                hcur[m * 2048 + jc] = (__bf16)(og * tanh_f(cn));
            }
        }
        __syncthreads();                 // drain h_a stores (vmcnt) per wave
        if (tid == 0) signal_inc(cA);

        // ---- phase 1: gates_b = [h_a(t) | h_b(t-1)] @ [Wi1|Wh1]^T + b1 -----
        if (tid == 0) { spin_ge(cA, 32 * (t + 1)); spin_ge(cB, 32 * t); }
        __syncthreads();
        kloop<2048, true>(hcur, hprev, W1p, n0, m0, tid, Alds, Blds, acc);

        #pragma unroll
        for (int mi = 0; mi < 2; ++mi) {
            #pragma unroll
            for (int r = 0; r < 4; ++r) {
                int m = m0 + wm * 32 + mi * 16 + lq * 4 + r;
                float pre[4];
                #pragma unroll
                for (int g = 0; g < 4; ++g)
                    pre[g] = acc[mi][g][r] + Aux1[wn * 64 + g * 16 + lj];
                float ig = sigm_f(pre[0]);
                float fg = sigm_f(pre[1]);
                float gv = tanh_f(pre[2]);
                float og = sigm_f(pre[3]);
                float cn = fg * c1[mi][r] + ig * gv;
                c1[mi][r] = cn;
                hcur[m * 2048 + 1024 + jc] = (__bf16)(og * tanh_f(cn));
            }
        }
        __syncthreads();
        if (tid == 0) signal_inc(cB);
    }

    // ---- final FC: pred = h_b(127) @ Wfc^T + bfc  (blocks nb<6 only) -------
    if (nb < 6) {
        if (tid == 0) spin_ge(cB, 32 * 128);
        __syncthreads();
        if (tid < 128) {
            int n = n0 + tid;
            Aux1[tid] = (n < 672) ? bfc[n] : 0.f;
        }
        // h_b(127) is in Ab0 (t=127 odd -> hcur=Ab0), cols 1024..2047
        kloop<1024, false>(Ab0 + 1024, nullptr, Wfcp, n0, m0, tid, Alds, Blds, acc);
        #pragma unroll
        for (int mi = 0; mi < 2; ++mi) {
            #pragma unroll
            for (int r = 0; r < 4; ++r) {
                int m = m0 + wm * 32 + mi * 16 + lq * 4 + r;
                #pragma unroll
                for (int ni = 0; ni < 4; ++ni) {
                    int n = n0 + wn * 64 + ni * 16 + lj;
                    if (n < 672)
                        out[m * 672 + n] = acc[mi][ni][r] + Aux1[wn * 64 + ni * 16 + lj];
                }
            }
        }
    }
}

// ---------------- workspace layout (bytes) ----------------------------------
#define O_W0P   0u            // 4096*1024*2  = 8388608
#define O_W1P   8388608u      // 4096*2048*2  = 16777216
#define O_WFCP  25165824u     // 768*1024*2   = 1572864
#define O_WI0P  26738688u     // 4096*8*4     = 131072
#define O_B1P   26869760u     // 4096*4       = 16384
#define O_AB0   26886144u     // 512*2048*2   = 2097152   (zeroed: h(-1)=0)
#define O_CNT   28983296u     // 16*4 -> padded 4096      (zeroed)
#define O_AB1   28987392u     // 512*2048*2   = 2097152
#define WS_NEED 31084544u

extern "C" void kernel_launch(void* const* d_in, const int* in_sizes, int n_in,
                              void* d_out, int out_size, void* d_ws, size_t ws_size,
                              hipStream_t stream) {
    const float* x   = (const float*)d_in[0];
    const float* Wi0 = (const float*)d_in[1];
    const float* Wh0 = (const float*)d_in[2];
    const float* b0  = (const float*)d_in[3];
    const float* Wi1 = (const float*)d_in[4];
    const float* Wh1 = (const float*)d_in[5];
    const float* b1  = (const float*)d_in[6];
    const float* Wfc = (const float*)d_in[7];
    const float* bfc = (const float*)d_in[8];
    float* out = (float*)d_out;
    char*  ws  = (char*)d_ws;
    if (ws_size < WS_NEED) return;

    __bf16* W0p  = (__bf16*)(ws + O_W0P);
    __bf16* W1p  = (__bf16*)(ws + O_W1P);
    __bf16* Wfcp = (__bf16*)(ws + O_WFCP);
    float*  Wi0p = (float*)(ws + O_WI0P);
    float*  b1p  = (float*)(ws + O_B1P);
    __bf16* Ab0  = (__bf16*)(ws + O_AB0);
    int*    cnt  = (int*)(ws + O_CNT);
    __bf16* Ab1  = (__bf16*)(ws + O_AB1);

    // zero h(-1) buffer + sync counters (contiguous region)
    hipMemsetAsync(ws + O_AB0, 0, 2097152u + 4096u, stream);

    prep_w0   <<<4096, 256, 0, stream>>>(Wh0, W0p);
    prep_w1   <<<8192, 256, 0, stream>>>(Wi1, Wh1, W1p);
    prep_wfc  <<<768,  256, 0, stream>>>(Wfc, Wfcp);
    prep_small<<<16,   256, 0, stream>>>(Wi0, b0, b1, Wi0p, b1p);

    dim3 blk(256), grid(32, 8);
    lstm_persist<<<grid, blk, 0, stream>>>(x, W0p, W1p, Wfcp, Wi0p, b1p, bfc,
                                           Ab0, Ab1, cnt, out);
}